// Round 14
// baseline (258.111 us; speedup 1.0000x reference)
//
#include <hip/hip_runtime.h>
#include <math.h>

#define BB 4
#define QQ 200
#define NN 32
#define HWV 65536
#define NCLS 80
#define QT7 7           // ceil(200/32) q-tiles of 32
#define LN2 0.69314718055995f
#define SS 256          // k-slices per (b, qt)
#define CHUNKK 256      // k per wave
#define NH 8            // half-steps per wave (32 k each)
#define WPB 4           // waves per block (independent k-slices, no barriers)
#define LDH 72          // bf16 per LDS row: 64 data + 8 pad -> 144B stride (measured 0 conflicts)

typedef __bf16 bf16x8 __attribute__((ext_vector_type(8)));
typedef __bf16 bf16x4 __attribute__((ext_vector_type(4)));
typedef float f32x16 __attribute__((ext_vector_type(16)));
typedef float f32x4 __attribute__((ext_vector_type(4)));

__device__ __forceinline__ float bflo(unsigned u) {
  union { unsigned i; float f; } c; c.i = u << 16; return c.f;
}
__device__ __forceinline__ float bfhi(unsigned u) {
  union { unsigned i; float f; } c; c.i = u & 0xffff0000u; return c.f;
}

// ---------------- main MFMA kernel, half-tile reg->LDS staged ----------------
// grid (SS/WPB, QT7, BB), 256 threads. Each wave = one k-slice of 256 for a
// 32q x 32n tile; waves fully independent (no __syncthreads).
// EXACT r11-winning hot loop (NH=8, SS=256, 81.9us, no spills) + fused per-row
// t-sums on qt==0 waves (code validated cost-free in r9 bench, correctness
// validated in r12 bench). tsum_kernel's 33.5MB re-read is eliminated.
__global__ __launch_bounds__(256, 2) void main_kernel(
    const float* __restrict__ pred_masks, const float* __restrict__ gt_masks,
    __bf16* __restrict__ pD, __bf16* __restrict__ pS, float* __restrict__ pQs,
    float* __restrict__ pT) {
  __shared__ __bf16 xls[WPB][32][LDH];   // 4.6 KB/wave
  __shared__ __bf16 tls[WPB][32][LDH];   // 4.6 KB/wave

  const int tid = threadIdx.x;
  const int w = tid >> 6, lane = tid & 63;
  const int sIdx = blockIdx.x * WPB + w;
  const int qt = blockIdx.y, b = blockIdx.z;
  const int rc = lane & 31, half = lane >> 5;
  const int l8r = lane >> 3, l8c = lane & 7;   // staging: 8 rows x 8 chunks(16B)
  const bool doT = (qt == 0);
  const int k0 = sIdx * CHUNKK;

  // byte offsets: row stride = HWV*4B = 1<<18
  const char* baseA = (const char*)(pred_masks + (size_t)b * QQ * HWV + k0) + l8c * 16;
  const char* baseT = (const char*)(gt_masks + (size_t)b * NN * HWV + k0) + l8c * 16;
  unsigned aoff[4], toff[4];
#pragma unroll
  for (int i = 0; i < 4; ++i) {
    int ar = qt * 32 + 8 * i + l8r;
    if (ar > QQ - 1) ar = QQ - 1;        // pad rows duplicate row 199 (discarded)
    aoff[i] = (unsigned)ar << 18;
    toff[i] = (unsigned)(8 * i + l8r) << 18;
  }

  f32x16 accD, accS;
#pragma unroll
  for (int r = 0; r < 16; ++r) { accD[r] = 0.f; accS[r] = 0.f; }
  float ssum = 0.f, xsum = 0.f, lgsum = 0.f, tsl = 0.f;

  f32x4 av[4], tv[4];
  auto LOADH = [&](int h) {
#pragma unroll
    for (int i = 0; i < 4; ++i)
      av[i] = __builtin_nontemporal_load(
          reinterpret_cast<const f32x4*>(baseA + aoff[i] + h * 128));
#pragma unroll
    for (int i = 0; i < 4; ++i)
      tv[i] = *reinterpret_cast<const f32x4*>(baseT + toff[i] + h * 128);
  };

  char* xb = (char*)&xls[w][0][0];
  char* tb = (char*)&tls[w][0][0];

  LOADH(0);
#pragma unroll
  for (int h = 0; h < NH; ++h) {
    const int sub = (h & 1) * 64;   // which 64B half of the 144B row
    // ---- stage current half (consumes av/tv via reg-dependency waits) ----
#pragma unroll
    for (int i = 0; i < 4; ++i) {
      int row = 8 * i + l8r;
      f32x4 x = av[i];
      bf16x4 xv = {(__bf16)x.x, (__bf16)x.y, (__bf16)x.z, (__bf16)x.w};
      *reinterpret_cast<bf16x4*>(xb + row * 144 + sub + l8c * 8) = xv;
      f32x4 t = tv[i];
      bf16x4 tv4 = {(__bf16)t.x, (__bf16)t.y, (__bf16)t.z, (__bf16)t.w};
      *reinterpret_cast<bf16x4*>(tb + row * 144 + sub + l8c * 8) = tv4;
    }
    // ---- reissue loads for next half (in flight during compute) ----
    if (h + 1 < NH) LOADH(h + 1);
    // ---- fragments + transform + MFMA (same-wave DS ordering is in-order) ----
#pragma unroll
    for (int ks2 = 0; ks2 < 2; ++ks2) {
      int off = rc * 144 + sub + ks2 * 32 + half * 16;
      bf16x8 xf = *reinterpret_cast<const bf16x8*>(xb + off);
      bf16x8 tf = *reinterpret_cast<const bf16x8*>(tb + off);
      bf16x8 sf;
      float p0 = 1.f, p1 = 1.f;
#pragma unroll
      for (int j = 0; j < 8; ++j) {
        float x = (float)xf[j];
        float e = __expf(-x);                  // |x| <~ 6 for N(0,1) inputs
        float a = 1.f + e;
        float s = __builtin_amdgcn_rcpf(a);    // sigmoid(x)
        sf[j] = (__bf16)s;
        ssum += s;
        xsum += x;
        if (j < 4) p0 *= a; else p1 *= a;      // two chains for ILP
      }
      lgsum += __log2f(p0 * p1);               // prod8 < 3e20, fp32-safe
      if (doT) {
        // per-row t sums: tf covers row rc; lanes l, l^32 cover disjoint k
#pragma unroll
        for (int j = 0; j < 8; ++j) tsl += (float)tf[j];
      }
      accD = __builtin_amdgcn_mfma_f32_32x32x16_bf16(xf, tf, accD, 0, 0, 0);
      accS = __builtin_amdgcn_mfma_f32_32x32x16_bf16(sf, tf, accS, 0, 0, 0);
    }
  }

  // lanes l, l^32 hold the two k-halves of row rc
  ssum += __shfl_xor(ssum, 32);
  xsum += __shfl_xor(xsum, 32);
  lgsum += __shfl_xor(lgsum, 32);

  const size_t tile32 = (size_t)(b * QT7 + qt);
  if (lane < 32) {
    float* pq = pQs + ((tile32 * 32 + rc) * (size_t)SS + sIdx) * 2;
    pq[0] = ssum;                       // sum of sigmoid over slice
    pq[1] = -xsum - LN2 * lgsum;        // sum of log(1-sigmoid)
  }
  if (doT) {
    tsl += __shfl_xor(tsl, 32);
    if (lane < 32) pT[((size_t)b * SS + sIdx) * NN + rc] = tsl;
  }
#pragma unroll
  for (int r = 0; r < 16; ++r) {
    int row = (r & 3) + 8 * (r >> 2) + 4 * half;   // verified C/D map
    size_t o = ((tile32 * 32 + row) * (size_t)SS + sIdx) * 32 + rc;  // [q][s][n]
    pD[o] = (__bf16)accD[r];
    pS[o] = (__bf16)accS[r];
  }
}

// ---------------- reduce t partials: tsum[b][n] = sum_s pT[b][s][n] ----------------
__global__ __launch_bounds__(64) void treduce_kernel(const float* __restrict__ pT,
                                                     float* __restrict__ tsum) {
  int b = blockIdx.x;
  int n = threadIdx.x & 31, sg = threadIdx.x >> 5;
  float acc = 0.f;
  for (int s = sg; s < SS; s += 2) acc += pT[((size_t)b * SS + s) * NN + n];
  acc += __shfl_xor(acc, 32);
  if (threadIdx.x < 32) tsum[b * NN + n] = acc;
}

// ---------------- reduce + combine ----------------
__global__ __launch_bounds__(256) void combine_kernel(
    const float* __restrict__ pred_logits, const int* __restrict__ gt_classes,
    const __bf16* __restrict__ pD, const __bf16* __restrict__ pS,
    const float* __restrict__ pQs, const float* __restrict__ tsum,
    float* __restrict__ out) {
  __shared__ float redD[32][33];
  __shared__ float redS[32][33];
  __shared__ float redQ[4][2];
  int bq = blockIdx.x;
  int b = bq / QQ, q = bq % QQ;
  int qt = q >> 5, qi = q & 31;
  int tid = threadIdx.x;
  int sg = tid >> 3, nq = tid & 7;  // 32 s-groups x 8 n-quads
  size_t rowbase = ((size_t)(b * QT7 + qt) * 32 + qi) * (size_t)SS;
  float dD[4] = {0.f, 0.f, 0.f, 0.f}, dS4[4] = {0.f, 0.f, 0.f, 0.f};
  for (int s = sg; s < SS; s += 32) {
    size_t o = (rowbase + s) * 32 + nq * 4;
    uint2 ud = *reinterpret_cast<const uint2*>(pD + o);
    uint2 us = *reinterpret_cast<const uint2*>(pS + o);
    dD[0] += bflo(ud.x); dD[1] += bfhi(ud.x); dD[2] += bflo(ud.y); dD[3] += bfhi(ud.y);
    dS4[0] += bflo(us.x); dS4[1] += bfhi(us.x); dS4[2] += bflo(us.y); dS4[3] += bfhi(us.y);
  }
#pragma unroll
  for (int j = 0; j < 4; ++j) {
    redD[sg][nq * 4 + j] = dD[j];
    redS[sg][nq * 4 + j] = dS4[j];
  }
  float sS = 0.f, sL = 0.f;
  for (int s = tid; s < SS; s += 256) {
    const float* pq = pQs + (rowbase + s) * 2;
    sS += pq[0];
    sL += pq[1];
  }
#pragma unroll
  for (int m = 1; m < 64; m <<= 1) { sS += __shfl_xor(sS, m); sL += __shfl_xor(sL, m); }
  if ((tid & 63) == 0) { redQ[tid >> 6][0] = sS; redQ[tid >> 6][1] = sL; }
  __syncthreads();
  if (tid < 32) {
    int n = tid;
    float tD = 0.f, tS = 0.f;
#pragma unroll 8
    for (int g = 0; g < 32; ++g) { tD += redD[g][n]; tS += redS[g][n]; }
    float fsS = (redQ[0][0] + redQ[1][0]) + (redQ[2][0] + redQ[3][0]);
    float fsL = (redQ[0][1] + redQ[1][1]) + (redQ[2][1] + redQ[3][1]);
    int cls = gt_classes[b * NN + n];
    float logit = pred_logits[((size_t)(b * QQ + q)) * NCLS + cls];
    float prob = 1.f / (1.f + __expf(-logit));
    float bce = -(tD + fsL) * (1.f / (float)HWV);
    float dice = 1.f - 2.f * tS / (fsS + tsum[b * NN + n] + 1e-6f);
    float c = -prob + 5.f * bce + 5.f * dice;
    if (!isfinite(c)) c = 10000.f;
    out[(size_t)bq * NN + n] = c;
  }
}

extern "C" void kernel_launch(void* const* d_in, const int* in_sizes, int n_in,
                              void* d_out, int out_size, void* d_ws, size_t ws_size,
                              hipStream_t stream) {
  const float* pred_logits = (const float*)d_in[0];
  const float* pred_masks  = (const float*)d_in[1];
  const int*   gt_classes  = (const int*)d_in[2];
  const float* gt_masks    = (const float*)d_in[3];
  float* out = (float*)d_out;

  // workspace: ~31.4 MB
  __bf16* pD = (__bf16*)d_ws;
  __bf16* pS = pD + (size_t)BB * QT7 * SS * 1024;
  float* pQs = (float*)(pS + (size_t)BB * QT7 * SS * 1024);
  float* pT = pQs + (size_t)BB * QT7 * 32 * SS * 2;
  float* tsum = pT + (size_t)BB * SS * NN;

  main_kernel<<<dim3(SS / WPB, QT7, BB), WPB * 64, 0, stream>>>(
      pred_masks, gt_masks, pD, pS, pQs, pT);
  treduce_kernel<<<BB, 64, 0, stream>>>(pT, tsum);
  combine_kernel<<<BB * QQ, 256, 0, stream>>>(pred_logits, gt_classes, pD, pS, pQs,
                                              tsum, out);
}

// Round 15
// 69.812 us; speedup vs baseline: 3.6972x; 3.6972x over previous
//
#include <hip/hip_runtime.h>
#include <math.h>

#define BB 4
#define QQ 200
#define NN 32
#define HWV 65536
#define NCLS 80
#define QT7 7           // ceil(200/32) q-tiles of 32
#define LN2 0.69314718055995f
#define SS 256          // k-slices per (b, qt)
#define CHUNKK 256      // k per wave
#define NH 8            // half-steps per wave (32 k each)
#define WPB 4           // waves per block (independent k-slices, no barriers)
#define LDH 72          // bf16 per LDS row: 64 data + 8 pad -> 144B stride (measured 0 conflicts)

typedef __bf16 bf16x8 __attribute__((ext_vector_type(8)));
typedef __bf16 bf16x4 __attribute__((ext_vector_type(4)));
typedef float f32x16 __attribute__((ext_vector_type(16)));
typedef float f32x4 __attribute__((ext_vector_type(4)));

__device__ __forceinline__ float bflo(unsigned u) {
  union { unsigned i; float f; } c; c.i = u << 16; return c.f;
}
__device__ __forceinline__ float bfhi(unsigned u) {
  union { unsigned i; float f; } c; c.i = u & 0xffff0000u; return c.f;
}

// ---------------- main MFMA kernel, half-tile reg->LDS staged ----------------
// r11-WINNING KERNEL, VERBATIM (81.9us total, no spills). The live set sits
// at the 128-VGPR cliff: r10/r12/r14 each perturbed it (deeper unroll / outer
// loop / one extra accumulator) and all spilled to 3x slowdowns. DO NOT TOUCH.
__global__ __launch_bounds__(256, 2) void main_kernel(
    const float* __restrict__ pred_masks, const float* __restrict__ gt_masks,
    __bf16* __restrict__ pD, __bf16* __restrict__ pS, float* __restrict__ pQs) {
  __shared__ __bf16 xls[WPB][32][LDH];   // 4.6 KB/wave
  __shared__ __bf16 tls[WPB][32][LDH];   // 4.6 KB/wave

  const int tid = threadIdx.x;
  const int w = tid >> 6, lane = tid & 63;
  const int sIdx = blockIdx.x * WPB + w;
  const int qt = blockIdx.y, b = blockIdx.z;
  const int rc = lane & 31, half = lane >> 5;
  const int l8r = lane >> 3, l8c = lane & 7;   // staging: 8 rows x 8 chunks(16B)
  const int k0 = sIdx * CHUNKK;

  // byte offsets: row stride = HWV*4B = 1<<18
  const char* baseA = (const char*)(pred_masks + (size_t)b * QQ * HWV + k0) + l8c * 16;
  const char* baseT = (const char*)(gt_masks + (size_t)b * NN * HWV + k0) + l8c * 16;
  unsigned aoff[4], toff[4];
#pragma unroll
  for (int i = 0; i < 4; ++i) {
    int ar = qt * 32 + 8 * i + l8r;
    if (ar > QQ - 1) ar = QQ - 1;        // pad rows duplicate row 199 (discarded)
    aoff[i] = (unsigned)ar << 18;
    toff[i] = (unsigned)(8 * i + l8r) << 18;
  }

  f32x16 accD, accS;
#pragma unroll
  for (int r = 0; r < 16; ++r) { accD[r] = 0.f; accS[r] = 0.f; }
  float ssum = 0.f, xsum = 0.f, lgsum = 0.f;

  f32x4 av[4], tv[4];
  auto LOADH = [&](int h) {
#pragma unroll
    for (int i = 0; i < 4; ++i)
      av[i] = __builtin_nontemporal_load(
          reinterpret_cast<const f32x4*>(baseA + aoff[i] + h * 128));
#pragma unroll
    for (int i = 0; i < 4; ++i)
      tv[i] = *reinterpret_cast<const f32x4*>(baseT + toff[i] + h * 128);
  };

  char* xb = (char*)&xls[w][0][0];
  char* tb = (char*)&tls[w][0][0];

  LOADH(0);
#pragma unroll
  for (int h = 0; h < NH; ++h) {
    const int sub = (h & 1) * 64;   // which 64B half of the 144B row
    // ---- stage current half (consumes av/tv via reg-dependency waits) ----
#pragma unroll
    for (int i = 0; i < 4; ++i) {
      int row = 8 * i + l8r;
      f32x4 x = av[i];
      bf16x4 xv = {(__bf16)x.x, (__bf16)x.y, (__bf16)x.z, (__bf16)x.w};
      *reinterpret_cast<bf16x4*>(xb + row * 144 + sub + l8c * 8) = xv;
      f32x4 t = tv[i];
      bf16x4 tv4 = {(__bf16)t.x, (__bf16)t.y, (__bf16)t.z, (__bf16)t.w};
      *reinterpret_cast<bf16x4*>(tb + row * 144 + sub + l8c * 8) = tv4;
    }
    // ---- reissue loads for next half (in flight during compute) ----
    if (h + 1 < NH) LOADH(h + 1);
    // ---- fragments + transform + MFMA (same-wave DS ordering is in-order) ----
#pragma unroll
    for (int ks2 = 0; ks2 < 2; ++ks2) {
      int off = rc * 144 + sub + ks2 * 32 + half * 16;
      bf16x8 xf = *reinterpret_cast<const bf16x8*>(xb + off);
      bf16x8 tf = *reinterpret_cast<const bf16x8*>(tb + off);
      bf16x8 sf;
      float p0 = 1.f, p1 = 1.f;
#pragma unroll
      for (int j = 0; j < 8; ++j) {
        float x = (float)xf[j];
        float e = __expf(-x);                  // |x| <~ 6 for N(0,1) inputs
        float a = 1.f + e;
        float s = __builtin_amdgcn_rcpf(a);    // sigmoid(x)
        sf[j] = (__bf16)s;
        ssum += s;
        xsum += x;
        if (j < 4) p0 *= a; else p1 *= a;      // two chains for ILP
      }
      lgsum += __log2f(p0 * p1);               // prod8 < 3e20, fp32-safe
      accD = __builtin_amdgcn_mfma_f32_32x32x16_bf16(xf, tf, accD, 0, 0, 0);
      accS = __builtin_amdgcn_mfma_f32_32x32x16_bf16(sf, tf, accS, 0, 0, 0);
    }
  }

  // lanes l, l^32 hold the two k-halves of row rc
  ssum += __shfl_xor(ssum, 32);
  xsum += __shfl_xor(xsum, 32);
  lgsum += __shfl_xor(lgsum, 32);

  const size_t tile32 = (size_t)(b * QT7 + qt);
  if (lane < 32) {
    float* pq = pQs + ((tile32 * 32 + rc) * (size_t)SS + sIdx) * 2;
    pq[0] = ssum;                       // sum of sigmoid over slice
    pq[1] = -xsum - LN2 * lgsum;        // sum of log(1-sigmoid)
  }
#pragma unroll
  for (int r = 0; r < 16; ++r) {
    int row = (r & 3) + 8 * (r >> 2) + 4 * half;   // verified C/D map
    size_t o = ((tile32 * 32 + row) * (size_t)SS + sIdx) * 32 + rc;  // [q][s][n]
    pD[o] = (__bf16)accD[r];
    pS[o] = (__bf16)accS[r];
  }
}

// ---------------- t column sums, quarter-row blocks for full occupancy ----------------
// r11 used 128 blocks on 256 CUs (half idle, ~10us). 512 blocks each sum a
// 64KB quarter-row -> full CU coverage and BW; combine adds the 4 partials.
__global__ __launch_bounds__(256) void tsum4_kernel(const float* __restrict__ gt,
                                                    float* __restrict__ tsumq) {
  int bn = blockIdx.x >> 2, quarter = blockIdx.x & 3;
  const float* p = gt + (size_t)bn * HWV + quarter * (HWV / 4);
  float acc = 0.f;
#pragma unroll 4
  for (int k = threadIdx.x * 4; k < HWV / 4; k += 256 * 4) {
    f32x4 v = *reinterpret_cast<const f32x4*>(p + k);
    acc += (v.x + v.y) + (v.z + v.w);
  }
#pragma unroll
  for (int m = 1; m < 64; m <<= 1) acc += __shfl_xor(acc, m);
  __shared__ float wsum[4];
  if ((threadIdx.x & 63) == 0) wsum[threadIdx.x >> 6] = acc;
  __syncthreads();
  if (threadIdx.x == 0)
    tsumq[blockIdx.x] = (wsum[0] + wsum[1]) + (wsum[2] + wsum[3]);
}

// ---------------- reduce + combine ----------------
__global__ __launch_bounds__(256) void combine_kernel(
    const float* __restrict__ pred_logits, const int* __restrict__ gt_classes,
    const __bf16* __restrict__ pD, const __bf16* __restrict__ pS,
    const float* __restrict__ pQs, const float* __restrict__ tsumq,
    float* __restrict__ out) {
  __shared__ float redD[32][33];
  __shared__ float redS[32][33];
  __shared__ float redQ[4][2];
  int bq = blockIdx.x;
  int b = bq / QQ, q = bq % QQ;
  int qt = q >> 5, qi = q & 31;
  int tid = threadIdx.x;
  int sg = tid >> 3, nq = tid & 7;  // 32 s-groups x 8 n-quads
  size_t rowbase = ((size_t)(b * QT7 + qt) * 32 + qi) * (size_t)SS;
  float dD[4] = {0.f, 0.f, 0.f, 0.f}, dS4[4] = {0.f, 0.f, 0.f, 0.f};
  for (int s = sg; s < SS; s += 32) {
    size_t o = (rowbase + s) * 32 + nq * 4;
    uint2 ud = *reinterpret_cast<const uint2*>(pD + o);
    uint2 us = *reinterpret_cast<const uint2*>(pS + o);
    dD[0] += bflo(ud.x); dD[1] += bfhi(ud.x); dD[2] += bflo(ud.y); dD[3] += bfhi(ud.y);
    dS4[0] += bflo(us.x); dS4[1] += bfhi(us.x); dS4[2] += bflo(us.y); dS4[3] += bfhi(us.y);
  }
#pragma unroll
  for (int j = 0; j < 4; ++j) {
    redD[sg][nq * 4 + j] = dD[j];
    redS[sg][nq * 4 + j] = dS4[j];
  }
  float sS = 0.f, sL = 0.f;
  for (int s = tid; s < SS; s += 256) {
    const float* pq = pQs + (rowbase + s) * 2;
    sS += pq[0];
    sL += pq[1];
  }
#pragma unroll
  for (int m = 1; m < 64; m <<= 1) { sS += __shfl_xor(sS, m); sL += __shfl_xor(sL, m); }
  if ((tid & 63) == 0) { redQ[tid >> 6][0] = sS; redQ[tid >> 6][1] = sL; }
  __syncthreads();
  if (tid < 32) {
    int n = tid;
    float tD = 0.f, tS = 0.f;
#pragma unroll 8
    for (int g = 0; g < 32; ++g) { tD += redD[g][n]; tS += redS[g][n]; }
    float fsS = (redQ[0][0] + redQ[1][0]) + (redQ[2][0] + redQ[3][0]);
    float fsL = (redQ[0][1] + redQ[1][1]) + (redQ[2][1] + redQ[3][1]);
    const float* t4 = tsumq + (size_t)(b * NN + n) * 4;
    float tsum = (t4[0] + t4[1]) + (t4[2] + t4[3]);
    int cls = gt_classes[b * NN + n];
    float logit = pred_logits[((size_t)(b * QQ + q)) * NCLS + cls];
    float prob = 1.f / (1.f + __expf(-logit));
    float bce = -(tD + fsL) * (1.f / (float)HWV);
    float dice = 1.f - 2.f * tS / (fsS + tsum + 1e-6f);
    float c = -prob + 5.f * bce + 5.f * dice;
    if (!isfinite(c)) c = 10000.f;
    out[(size_t)bq * NN + n] = c;
  }
}

extern "C" void kernel_launch(void* const* d_in, const int* in_sizes, int n_in,
                              void* d_out, int out_size, void* d_ws, size_t ws_size,
                              hipStream_t stream) {
  const float* pred_logits = (const float*)d_in[0];
  const float* pred_masks  = (const float*)d_in[1];
  const int*   gt_classes  = (const int*)d_in[2];
  const float* gt_masks    = (const float*)d_in[3];
  float* out = (float*)d_out;

  // workspace: ~31.2 MB
  __bf16* pD = (__bf16*)d_ws;
  __bf16* pS = pD + (size_t)BB * QT7 * SS * 1024;
  float* pQs = (float*)(pS + (size_t)BB * QT7 * SS * 1024);
  float* tsumq = pQs + (size_t)BB * QT7 * 32 * SS * 2;

  main_kernel<<<dim3(SS / WPB, QT7, BB), WPB * 64, 0, stream>>>(
      pred_masks, gt_masks, pD, pS, pQs);
  tsum4_kernel<<<BB * NN * 4, 256, 0, stream>>>(gt_masks, tsumq);
  combine_kernel<<<BB * QQ, 256, 0, stream>>>(pred_logits, gt_classes, pD, pS, pQs,
                                              tsumq, out);
}